// Round 1
// 123.881 us; speedup vs baseline: 1.0200x; 1.0200x over previous
//
#include <hip/hip_runtime.h>

// Packed parameter block in d_ws (floats):
//  [0    .. 255]   Vr[16][16]   (Re of V = U * diag((-i)^popcount(col)))
//  [256  .. 511]   Vi[16][16]
//  [512  .. 767]   WpT[64][4]   (WpT[f][q] = Wp[q][f])
//  [768  .. 771]   bp[4]
//  [772  .. 775]   pad (0)
//  [776  .. 1287]  MLP pack, stride 8: per j: {W1[j][0..3], b1[j], W2[j], 0, 0}
//  [1288]          b2;  [1289..1291] pad
#define CB_FLOATS 1292
#define CB_V4 (CB_FLOATS / 4)

// ---------------- precompute: build V and pack weights into ws ----------------

__device__ inline void gate_rz(float* ar, float* ai, int q, float th) {
    float c, s;
    __sincosf(0.5f * th, &s, &c);
    int st = 8 >> q;
    #pragma unroll
    for (int k = 0; k < 16; k++) {
        float r = ar[k], im = ai[k];
        if (k & st) {            // * e^{+i th/2}
            ar[k] = r * c - im * s;
            ai[k] = im * c + r * s;
        } else {                 // * e^{-i th/2}
            ar[k] = r * c + im * s;
            ai[k] = im * c - r * s;
        }
    }
}

__device__ inline void gate_ry(float* ar, float* ai, int q, float th) {
    float c, s;
    __sincosf(0.5f * th, &s, &c);
    int st = 8 >> q;
    #pragma unroll
    for (int k = 0; k < 16; k++) {
        if (!(k & st)) {
            int k1 = k | st;
            float r0 = ar[k], i0 = ai[k], r1 = ar[k1], i1 = ai[k1];
            ar[k]  = c * r0 - s * r1;  ai[k]  = c * i0 - s * i1;
            ar[k1] = s * r0 + c * r1;  ai[k1] = s * i0 + c * i1;
        }
    }
}

__device__ inline void gate_cnot(float* ar, float* ai, int c, int t) {
    int stc = 8 >> c, stt = 8 >> t;
    #pragma unroll
    for (int k = 0; k < 16; k++) {
        if ((k & stc) && !(k & stt)) {
            int k1 = k | stt;
            float r = ar[k], im = ai[k];
            ar[k] = ar[k1]; ai[k] = ai[k1];
            ar[k1] = r;     ai[k1] = im;
        }
    }
}

__global__ void precompute_kernel(const float* __restrict__ Wp,
                                  const float* __restrict__ bp,
                                  const float* __restrict__ wq,
                                  const float* __restrict__ W1,
                                  const float* __restrict__ b1,
                                  const float* __restrict__ W2,
                                  const float* __restrict__ b2,
                                  float* __restrict__ ws) {
    int t = threadIdx.x;  // 64 threads

    if (t < 16) {
        // Simulate the fixed part of the circuit on basis state e_t -> column t of U.
        float ar[16], ai[16];
        #pragma unroll
        for (int k = 0; k < 16; k++) { ar[k] = 0.f; ai[k] = 0.f; }
        ar[t] = 1.f;

        for (int layer = 0; layer < 2; layer++) {
            for (int q = 0; q < 4; q++) {
                const float* w = &wq[(layer * 4 + q) * 3];
                gate_rz(ar, ai, q, w[0]);
                gate_ry(ar, ai, q, w[1]);
                gate_rz(ar, ai, q, w[2]);
            }
            for (int c = 0; c < 3; c++) gate_cnot(ar, ai, c, c + 1);
        }

        // fold phase (-i)^popcount(t) of the RX product state into column t
        int pc = __popc(t) & 3;
        #pragma unroll
        for (int j = 0; j < 16; j++) {
            float re = ar[j], im = ai[j], vr, vi;
            switch (pc) {
                case 0: vr = re;  vi = im;  break;
                case 1: vr = im;  vi = -re; break;   // *(-i)
                case 2: vr = -re; vi = -im; break;   // *(-1)
                case 3: vr = -im; vi = re;  break;   // *(+i)
            }
            ws[j * 16 + t]       = vr;
            ws[256 + j * 16 + t] = vi;
        }
    }

    // WpT pack: ws[512 + f*4 + q] = Wp[q*64 + f], f = t
    for (int q = 0; q < 4; q++) ws[512 + t * 4 + q] = Wp[q * 64 + t];
    if (t < 4) ws[768 + t] = bp[t];
    if (t < 4) ws[772 + t] = 0.f;

    // MLP pack (stride 8), row j = t
    ws[776 + t * 8 + 0] = W1[t * 4 + 0];
    ws[776 + t * 8 + 1] = W1[t * 4 + 1];
    ws[776 + t * 8 + 2] = W1[t * 4 + 2];
    ws[776 + t * 8 + 3] = W1[t * 4 + 3];
    ws[776 + t * 8 + 4] = b1[t];
    ws[776 + t * 8 + 5] = W2[t];
    ws[776 + t * 8 + 6] = 0.f;
    ws[776 + t * 8 + 7] = 0.f;
    if (t == 0) { ws[1288] = b2[0]; ws[1289] = 0.f; ws[1290] = 0.f; ws[1291] = 0.f; }
}

// ---------------- main kernel ----------------
// One thread = one row. Each thread streams its own contiguous 256-B row of x
// as 16 float4 loads (full cache-line consumption, L1 reuse across the 16
// instructions). No LDS staging of x, no barriers in the hot path -> waves
// drift freely and memory issue overlaps the compute tail. All uniform
// parameters (V, WpT, MLP) are staged once per block into 5 KB of LDS and read
// as b128/b64 broadcasts (same-address across lanes = conflict-free).

__global__ __launch_bounds__(256, 4) void qmain_kernel(const float* __restrict__ x,
                                                       const float* __restrict__ cb,
                                                       float* __restrict__ out,
                                                       int B) {
    __shared__ __align__(16) float w[CB_FLOATS];
    const int t = threadIdx.x;
    {
        float4* dst = reinterpret_cast<float4*>(w);
        const float4* src = reinterpret_cast<const float4*>(cb);
        for (int i = t; i < CB_V4; i += 256) dst[i] = src[i];
    }
    __syncthreads();

    const int row = blockIdx.x * 256 + t;
    if (row >= B) return;

    const float4* __restrict__ xr = reinterpret_cast<const float4*>(x + (size_t)row * 64);

    // ---- angles = WpT^T * x_row + bp ----
    float ang0 = w[768], ang1 = w[769], ang2 = w[770], ang3 = w[771];
    #pragma unroll 4
    for (int i = 0; i < 16; i++) {
        float4 v = xr[i];
        const float4* wt = reinterpret_cast<const float4*>(&w[512 + i * 16]);
        float4 w0 = wt[0], w1 = wt[1], w2 = wt[2], w3 = wt[3];
        ang0 = fmaf(v.x, w0.x, fmaf(v.y, w1.x, fmaf(v.z, w2.x, fmaf(v.w, w3.x, ang0))));
        ang1 = fmaf(v.x, w0.y, fmaf(v.y, w1.y, fmaf(v.z, w2.y, fmaf(v.w, w3.y, ang1))));
        ang2 = fmaf(v.x, w0.z, fmaf(v.y, w1.z, fmaf(v.z, w2.z, fmaf(v.w, w3.z, ang2))));
        ang3 = fmaf(v.x, w0.w, fmaf(v.y, w1.w, fmaf(v.z, w2.w, fmaf(v.w, w3.w, ang3))));
    }

    // ---- RX product-state magnitudes m[16] ----
    float c0, s0, c1, s1, c2, s2, c3, s3;
    __sincosf(0.5f * ang0, &s0, &c0);
    __sincosf(0.5f * ang1, &s1, &c1);
    __sincosf(0.5f * ang2, &s2, &c2);
    __sincosf(0.5f * ang3, &s3, &c3);
    float pre[4]  = { c0 * c1, c0 * s1, s0 * c1, s0 * s1 };
    float post[4] = { c2 * c3, c2 * s3, s2 * c3, s2 * s3 };
    float m[16];
    #pragma unroll
    for (int k = 0; k < 16; k++) m[k] = pre[k >> 2] * post[k & 3];

    // ---- phi = V m ; p = |phi|^2 ; z = signed sums ----
    float z0 = 0.f, z1 = 0.f, z2 = 0.f, z3 = 0.f;
    #pragma unroll
    for (int j = 0; j < 16; j++) {
        const float4* vr = reinterpret_cast<const float4*>(&w[j * 16]);
        const float4* vi = reinterpret_cast<const float4*>(&w[256 + j * 16]);
        float re = 0.f, im = 0.f;
        #pragma unroll
        for (int k4 = 0; k4 < 4; k4++) {
            float4 a = vr[k4];
            float4 b = vi[k4];
            re = fmaf(a.x, m[4 * k4 + 0], re);
            re = fmaf(a.y, m[4 * k4 + 1], re);
            re = fmaf(a.z, m[4 * k4 + 2], re);
            re = fmaf(a.w, m[4 * k4 + 3], re);
            im = fmaf(b.x, m[4 * k4 + 0], im);
            im = fmaf(b.y, m[4 * k4 + 1], im);
            im = fmaf(b.z, m[4 * k4 + 2], im);
            im = fmaf(b.w, m[4 * k4 + 3], im);
        }
        float p = re * re + im * im;
        z0 += (j & 8) ? -p : p;
        z1 += (j & 4) ? -p : p;
        z2 += (j & 2) ? -p : p;
        z3 += (j & 1) ? -p : p;
    }

    // ---- MLP: out = W2 @ relu(W1 @ z + b1) + b2 ----
    float acc = w[1288];
    #pragma unroll
    for (int j = 0; j < 64; j++) {
        float4 a  = *reinterpret_cast<const float4*>(&w[776 + j * 8]);
        float2 bb = *reinterpret_cast<const float2*>(&w[776 + j * 8 + 4]);
        float h = fmaf(a.x, z0, fmaf(a.y, z1, fmaf(a.z, z2, fmaf(a.w, z3, bb.x))));
        h = fmaxf(h, 0.f);
        acc = fmaf(bb.y, h, acc);
    }
    out[row] = acc;
}

// ---------------- launch ----------------

extern "C" void kernel_launch(void* const* d_in, const int* in_sizes, int n_in,
                              void* d_out, int out_size, void* d_ws, size_t ws_size,
                              hipStream_t stream) {
    const float* x  = (const float*)d_in[0];
    const float* Wp = (const float*)d_in[1];
    const float* bp = (const float*)d_in[2];
    const float* wq = (const float*)d_in[3];
    const float* W1 = (const float*)d_in[4];
    const float* b1 = (const float*)d_in[5];
    const float* W2 = (const float*)d_in[6];
    const float* b2 = (const float*)d_in[7];
    float* ws = (float*)d_ws;
    float* out = (float*)d_out;

    int B = in_sizes[0] / 64;

    precompute_kernel<<<1, 64, 0, stream>>>(Wp, bp, wq, W1, b1, W2, b2, ws);

    int grid = (B + 255) / 256;
    qmain_kernel<<<grid, 256, 0, stream>>>(x, ws, out, B);
}

// Round 2
// 122.591 us; speedup vs baseline: 1.0307x; 1.0105x over previous
//
#include <hip/hip_runtime.h>

// Packed parameter block in d_ws (floats):
//  [0    .. 255]   Vr[16][16]   (Re of V = U * diag((-i)^popcount(col)))
//  [256  .. 511]   Vi[16][16]
//  [512  .. 767]   WpT[64][4]   (WpT[f][q] = Wp[q][f])
//  [768  .. 771]   bp[4]
//  [772  .. 775]   pad (0)
//  [776  .. 1287]  MLP pack, stride 8: per j: {W1[j][0..3], b1[j], W2[j], 0, 0}
//  [1288]          b2;  [1289..1291] pad
#define CB_FLOATS 1292

// ---------------- precompute: build V and pack weights into ws ----------------

__device__ inline void gate_rz(float* ar, float* ai, int q, float th) {
    float c, s;
    __sincosf(0.5f * th, &s, &c);
    int st = 8 >> q;
    #pragma unroll
    for (int k = 0; k < 16; k++) {
        float r = ar[k], im = ai[k];
        if (k & st) {            // * e^{+i th/2}
            ar[k] = r * c - im * s;
            ai[k] = im * c + r * s;
        } else {                 // * e^{-i th/2}
            ar[k] = r * c + im * s;
            ai[k] = im * c - r * s;
        }
    }
}

__device__ inline void gate_ry(float* ar, float* ai, int q, float th) {
    float c, s;
    __sincosf(0.5f * th, &s, &c);
    int st = 8 >> q;
    #pragma unroll
    for (int k = 0; k < 16; k++) {
        if (!(k & st)) {
            int k1 = k | st;
            float r0 = ar[k], i0 = ai[k], r1 = ar[k1], i1 = ai[k1];
            ar[k]  = c * r0 - s * r1;  ai[k]  = c * i0 - s * i1;
            ar[k1] = s * r0 + c * r1;  ai[k1] = s * i0 + c * i1;
        }
    }
}

__device__ inline void gate_cnot(float* ar, float* ai, int c, int t) {
    int stc = 8 >> c, stt = 8 >> t;
    #pragma unroll
    for (int k = 0; k < 16; k++) {
        if ((k & stc) && !(k & stt)) {
            int k1 = k | stt;
            float r = ar[k], im = ai[k];
            ar[k] = ar[k1]; ai[k] = ai[k1];
            ar[k1] = r;     ai[k1] = im;
        }
    }
}

__global__ void precompute_kernel(const float* __restrict__ Wp,
                                  const float* __restrict__ bp,
                                  const float* __restrict__ wq,
                                  const float* __restrict__ W1,
                                  const float* __restrict__ b1,
                                  const float* __restrict__ W2,
                                  const float* __restrict__ b2,
                                  float* __restrict__ ws) {
    int t = threadIdx.x;  // 64 threads

    if (t < 16) {
        // Simulate the fixed part of the circuit on basis state e_t -> column t of U.
        float ar[16], ai[16];
        #pragma unroll
        for (int k = 0; k < 16; k++) { ar[k] = 0.f; ai[k] = 0.f; }
        ar[t] = 1.f;

        for (int layer = 0; layer < 2; layer++) {
            for (int q = 0; q < 4; q++) {
                const float* w = &wq[(layer * 4 + q) * 3];
                gate_rz(ar, ai, q, w[0]);
                gate_ry(ar, ai, q, w[1]);
                gate_rz(ar, ai, q, w[2]);
            }
            for (int c = 0; c < 3; c++) gate_cnot(ar, ai, c, c + 1);
        }

        // fold phase (-i)^popcount(t) of the RX product state into column t
        int pc = __popc(t) & 3;
        #pragma unroll
        for (int j = 0; j < 16; j++) {
            float re = ar[j], im = ai[j], vr, vi;
            switch (pc) {
                case 0: vr = re;  vi = im;  break;
                case 1: vr = im;  vi = -re; break;   // *(-i)
                case 2: vr = -re; vi = -im; break;   // *(-1)
                case 3: vr = -im; vi = re;  break;   // *(+i)
            }
            ws[j * 16 + t]       = vr;
            ws[256 + j * 16 + t] = vi;
        }
    }

    // WpT pack: ws[512 + f*4 + q] = Wp[q*64 + f], f = t
    for (int q = 0; q < 4; q++) ws[512 + t * 4 + q] = Wp[q * 64 + t];
    if (t < 4) ws[768 + t] = bp[t];
    if (t < 4) ws[772 + t] = 0.f;

    // MLP pack (stride 8), row j = t
    ws[776 + t * 8 + 0] = W1[t * 4 + 0];
    ws[776 + t * 8 + 1] = W1[t * 4 + 1];
    ws[776 + t * 8 + 2] = W1[t * 4 + 2];
    ws[776 + t * 8 + 3] = W1[t * 4 + 3];
    ws[776 + t * 8 + 4] = b1[t];
    ws[776 + t * 8 + 5] = W2[t];
    ws[776 + t * 8 + 6] = 0.f;
    ws[776 + t * 8 + 7] = 0.f;
    if (t == 0) { ws[1288] = b2[0]; ws[1289] = 0.f; ws[1290] = 0.f; ws[1291] = 0.f; }
}

// ---------------- main kernel ----------------
// One thread = one row, but x is loaded COALESCED per wave: each wave owns 64
// consecutive rows (16 KB) and loads them in two 32-column chunks. Per load
// instruction the 64 lanes cover 8 FULL 128-B lines (8 lanes x 16 B per row
// half, rows at 256-B stride) -> every fetched line is fully consumed, x read
// exactly once. The chunk is transposed through a WAVE-PRIVATE LDS region
// ([64][33] f32: write banks 2-way, read banks (lane+i)%32 2-way -> free), so
// only s_waitcnt lgkmcnt is needed -- NO block barriers, waves drift freely
// and memory always overlaps compute across the 16 resident waves/CU.
// All uniform params are read straight from cb with compile-time offsets ->
// scalar loads on the K$ pipe (L2-hot), keeping the LDS pipe for the
// transpose and the VALU for math.

__global__ __launch_bounds__(256, 4) void qmain_kernel(const float* __restrict__ x,
                                                       const float* __restrict__ cb,
                                                       float* __restrict__ out,
                                                       int B) {
    __shared__ float xt[4][64 * 33];
    const int t = threadIdx.x;
    const int wave = t >> 6, lane = t & 63;
    float* __restrict__ myT = xt[wave];
    const int g = lane >> 3, h4 = (lane & 7) * 4;

    const long brow = (long)blockIdx.x * 256;
    const long row = brow + t;

    float ang0 = cb[768], ang1 = cb[769], ang2 = cb[770], ang3 = cb[771];

    if (brow + 256 <= (long)B) {
        const float* __restrict__ xw = x + (brow + (long)wave * 64) * 64;
        #pragma unroll
        for (int c = 0; c < 2; c++) {
            // cooperative coalesced load of 64 rows x cols [32c, 32c+32)
            #pragma unroll
            for (int k = 0; k < 8; k++) {
                int r = 8 * k + g;
                float4 v = *reinterpret_cast<const float4*>(xw + r * 64 + c * 32 + h4);
                float* d = &myT[r * 33 + h4];
                d[0] = v.x; d[1] = v.y; d[2] = v.z; d[3] = v.w;
            }
            asm volatile("s_waitcnt lgkmcnt(0)" ::: "memory");
            __builtin_amdgcn_sched_barrier(0);
            const float* mr = &myT[lane * 33];
            #pragma unroll
            for (int i = 0; i < 32; i++) {
                float xv = mr[i];
                const float* wp = &cb[512 + (c * 32 + i) * 4];
                ang0 = fmaf(xv, wp[0], ang0);
                ang1 = fmaf(xv, wp[1], ang1);
                ang2 = fmaf(xv, wp[2], ang2);
                ang3 = fmaf(xv, wp[3], ang3);
            }
            if (c == 0) {           // chunk-0 reads done before chunk-1 overwrites
                asm volatile("s_waitcnt lgkmcnt(0)" ::: "memory");
                __builtin_amdgcn_sched_barrier(0);
            }
        }
    } else {
        // tail fallback (never taken at B = 262144): per-thread direct stream
        if (row >= (long)B) return;
        const float4* __restrict__ xr = reinterpret_cast<const float4*>(x + row * 64);
        #pragma unroll
        for (int i = 0; i < 16; i++) {
            float4 v = xr[i];
            const float* wp = &cb[512 + i * 16];
            ang0 = fmaf(v.x, wp[0], fmaf(v.y, wp[4], fmaf(v.z, wp[8],  fmaf(v.w, wp[12], ang0))));
            ang1 = fmaf(v.x, wp[1], fmaf(v.y, wp[5], fmaf(v.z, wp[9],  fmaf(v.w, wp[13], ang1))));
            ang2 = fmaf(v.x, wp[2], fmaf(v.y, wp[6], fmaf(v.z, wp[10], fmaf(v.w, wp[14], ang2))));
            ang3 = fmaf(v.x, wp[3], fmaf(v.y, wp[7], fmaf(v.z, wp[11], fmaf(v.w, wp[15], ang3))));
        }
    }

    // ---- RX product-state magnitudes m[16] ----
    float c0, s0, c1, s1, c2, s2, c3, s3;
    __sincosf(0.5f * ang0, &s0, &c0);
    __sincosf(0.5f * ang1, &s1, &c1);
    __sincosf(0.5f * ang2, &s2, &c2);
    __sincosf(0.5f * ang3, &s3, &c3);
    float pre[4]  = { c0 * c1, c0 * s1, s0 * c1, s0 * s1 };
    float post[4] = { c2 * c3, c2 * s3, s2 * c3, s2 * s3 };
    float m[16];
    #pragma unroll
    for (int k = 0; k < 16; k++) m[k] = pre[k >> 2] * post[k & 3];

    // ---- phi = V m ; p = |phi|^2 ; z = signed sums ----
    float z0 = 0.f, z1 = 0.f, z2 = 0.f, z3 = 0.f;
    #pragma unroll
    for (int j = 0; j < 16; j++) {
        const float* vr = &cb[j * 16];
        const float* vi = &cb[256 + j * 16];
        float re = 0.f, im = 0.f;
        #pragma unroll
        for (int k = 0; k < 16; k++) {
            re = fmaf(vr[k], m[k], re);
            im = fmaf(vi[k], m[k], im);
        }
        float p = re * re + im * im;
        z0 += (j & 8) ? -p : p;
        z1 += (j & 4) ? -p : p;
        z2 += (j & 2) ? -p : p;
        z3 += (j & 1) ? -p : p;
    }

    // ---- MLP: out = W2 @ relu(W1 @ z + b1) + b2 ----
    float acc = cb[1288];
    #pragma unroll
    for (int j = 0; j < 64; j++) {
        const float* mp = &cb[776 + j * 8];
        float hdd = fmaf(mp[0], z0, fmaf(mp[1], z1, fmaf(mp[2], z2, fmaf(mp[3], z3, mp[4]))));
        hdd = fmaxf(hdd, 0.f);
        acc = fmaf(mp[5], hdd, acc);
    }
    out[row] = acc;
}

// ---------------- launch ----------------

extern "C" void kernel_launch(void* const* d_in, const int* in_sizes, int n_in,
                              void* d_out, int out_size, void* d_ws, size_t ws_size,
                              hipStream_t stream) {
    const float* x  = (const float*)d_in[0];
    const float* Wp = (const float*)d_in[1];
    const float* bp = (const float*)d_in[2];
    const float* wq = (const float*)d_in[3];
    const float* W1 = (const float*)d_in[4];
    const float* b1 = (const float*)d_in[5];
    const float* W2 = (const float*)d_in[6];
    const float* b2 = (const float*)d_in[7];
    float* ws = (float*)d_ws;
    float* out = (float*)d_out;

    int B = in_sizes[0] / 64;

    precompute_kernel<<<1, 64, 0, stream>>>(Wp, bp, wq, W1, b1, W2, b2, ws);

    int grid = (B + 255) / 256;
    qmain_kernel<<<grid, 256, 0, stream>>>(x, ws, out, B);
}